// Round 2
// baseline (886.025 us; speedup 1.0000x reference)
//
#include <hip/hip_runtime.h>
#include <hip/hip_cooperative_groups.h>

namespace cg = cooperative_groups;

#define B 4
#define N 2048
#define MAXIT 11       // bodies it = 0..10; it==11 is RT-only epilogue
#define TOL 1e-4f
#define NBLK 256
#define BT 256
#define CC 64          // candidates per nn tile
#define QPT 4          // queries per thread
#define QC (BT*QPT)    // 1024 queries per nn tile
#define RPB 32         // rows per block = B*N/NBLK

// ---------------- workspace layout ----------------
// [0,       98304)   float buf[B][N][3]            (temp point cloud, in-place)
// [98304,  163840)   unsigned long long nn[B][N]   (parity-encoded, never reset)
// [163840, 229376)   float part[4][B][64][16]      (rotating per-block partial sums)
// [229376, 229424)   float p1sum[B][3]

// ---------------- 3x3 helpers (double, thread-serial) ----------------
__device__ double det3(const double* M) {
    return M[0]*(M[4]*M[8]-M[5]*M[7])
         - M[1]*(M[3]*M[8]-M[5]*M[6])
         + M[2]*(M[3]*M[7]-M[4]*M[6]);
}

// SVD of 3x3 A (row-major): A = U * diag(sig) * V^T, sig sorted descending.
__device__ void svd3x3(const double* A, double* U, double* V, double* sig) {
    double S[9];
    for (int i = 0; i < 3; ++i)
        for (int j = 0; j < 3; ++j) {
            double s = 0.0;
            for (int k = 0; k < 3; ++k) s += A[k*3+i] * A[k*3+j];
            S[i*3+j] = s;
        }
    double Vm[9] = {1,0,0, 0,1,0, 0,0,1};
    for (int sweep = 0; sweep < 30; ++sweep) {
        double off = fabs(S[1]) + fabs(S[2]) + fabs(S[5]);
        double base = fabs(S[0]) + fabs(S[4]) + fabs(S[8]);
        if (off <= 1e-15 * base) break;
        for (int pi = 0; pi < 3; ++pi) {
            const int p = (pi == 2) ? 1 : 0;
            const int q = (pi == 0) ? 1 : 2;
            double apq = S[p*3+q];
            if (apq == 0.0) continue;
            double app = S[p*3+p], aqq = S[q*3+q];
            double tau = (aqq - app) / (2.0 * apq);
            double tt  = ((tau >= 0.0) ? 1.0 : -1.0) / (fabs(tau) + sqrt(1.0 + tau*tau));
            double c = 1.0 / sqrt(1.0 + tt*tt);
            double s = tt * c;
            for (int k = 0; k < 3; ++k) {
                double skp = S[k*3+p], skq = S[k*3+q];
                S[k*3+p] = c*skp - s*skq;
                S[k*3+q] = s*skp + c*skq;
            }
            for (int k = 0; k < 3; ++k) {
                double spk = S[p*3+k], sqk = S[q*3+k];
                S[p*3+k] = c*spk - s*sqk;
                S[q*3+k] = s*spk + c*sqk;
            }
            for (int k = 0; k < 3; ++k) {
                double vkp = Vm[k*3+p], vkq = Vm[k*3+q];
                Vm[k*3+p] = c*vkp - s*vkq;
                Vm[k*3+q] = s*vkp + c*vkq;
            }
        }
    }
    double lam[3] = {S[0], S[4], S[8]};
    int ord[3] = {0, 1, 2};
    for (int i = 0; i < 2; ++i)
        for (int j = i+1; j < 3; ++j)
            if (lam[ord[j]] > lam[ord[i]]) { int tmp = ord[i]; ord[i] = ord[j]; ord[j] = tmp; }
    for (int i = 0; i < 3; ++i) {
        int o = ord[i];
        double l = lam[o] > 0.0 ? lam[o] : 0.0;
        sig[i] = sqrt(l);
        for (int k = 0; k < 3; ++k) V[k*3+i] = Vm[k*3+o];
    }
    for (int i = 0; i < 3; ++i) {
        double u0 = 0, u1 = 0, u2 = 0;
        for (int k = 0; k < 3; ++k) {
            u0 += A[0*3+k] * V[k*3+i];
            u1 += A[1*3+k] * V[k*3+i];
            u2 += A[2*3+k] * V[k*3+i];
        }
        double nrm = sqrt(u0*u0 + u1*u1 + u2*u2);
        if (nrm > 1e-300) { u0 /= nrm; u1 /= nrm; u2 /= nrm; }
        else {
            double ax = U[0], ay = U[3], az = U[6];
            double bx = U[1], by = U[4], bz = U[7];
            u0 = ay*bz - az*by; u1 = az*bx - ax*bz; u2 = ax*by - ay*bx;
        }
        U[0*3+i] = u0; U[1*3+i] = u1; U[2*3+i] = u2;
    }
}

__device__ void compute_Rt(const double* H, const double* p1c, const double* p2c,
                           float* Rout, float* tout) {
    double U[9], V[9], sig[3];
    svd3x3(H, U, V, sig);
    double d = (det3(U) * det3(V) < 0.0) ? -1.0 : 1.0;
    V[2*3+2] *= d;
    double R[9];
    for (int i = 0; i < 3; ++i)
        for (int j = 0; j < 3; ++j) {
            double s = 0.0;
            for (int k = 0; k < 3; ++k) s += V[i*3+k] * U[j*3+k];
            R[i*3+j] = s;
        }
    for (int j = 0; j < 3; ++j) {
        double s = 0.0;
        for (int k = 0; k < 3; ++k) s += p1c[k] * R[k*3+j];
        tout[j] = (float)(p2c[j] - s);
    }
    for (int k = 0; k < 9; ++k) Rout[k] = (float)R[k];
}

__device__ inline float wred(float v) {
    v += __shfl_down(v, 32);
    v += __shfl_down(v, 16);
    v += __shfl_down(v, 8);
    v += __shfl_down(v, 4);
    v += __shfl_down(v, 2);
    v += __shfl_down(v, 1);
    return v;   // valid on lane 0 of each wave
}

__device__ __forceinline__ void tf_pt(const float* __restrict__ R, const float* __restrict__ T,
                                      float x, float y, float z,
                                      float& ox, float& oy, float& oz) {
    ox = x*R[0] + y*R[3] + z*R[6] + T[0];
    oy = x*R[1] + y*R[4] + z*R[7] + T[1];
    oz = x*R[2] + y*R[5] + z*R[8] + T[2];
}

// ---------------- single fused cooperative kernel ----------------
__global__ void __launch_bounds__(BT, 1)
icp_fused(const float* __restrict__ p1, const float* __restrict__ p2,
          float* __restrict__ out, float* __restrict__ buf,
          unsigned long long* __restrict__ nn,
          float* __restrict__ part, float* __restrict__ p1s) {
    cg::grid_group grid = cg::this_grid();
    const int bid = blockIdx.x, tid = threadIdx.x;
    const int b = bid >> 6, blk = bid & 63;      // batch, block-in-batch
    const int r0 = bid * RPB;                    // first owned global row
    const int lane = tid & 63, wave = tid >> 6;

    __shared__ float4 sc4[CC];
    __shared__ float sR[9], sT[3];
    __shared__ float lred[4][3];
    __shared__ int sCtl;

    // ---------- init ----------
    for (int j = tid; j < RPB*3; j += BT) buf[r0*3 + j] = p1[r0*3 + j];
    if (tid < RPB) nn[r0 + tid] = ~0ULL;
    if (blk == 0) {
        float sx = 0.f, sy = 0.f, sz = 0.f;
        for (int i = tid; i < N; i += BT) {
            const float* pp = &p1[(b*N + i)*3];
            sx += pp[0]; sy += pp[1]; sz += pp[2];
        }
        sx = wred(sx); sy = wred(sy); sz = wred(sz);
        if (lane == 0) { lred[wave][0]=sx; lred[wave][1]=sy; lred[wave][2]=sz; }
        __syncthreads();
        if (tid == 0) {
            p1s[b*3+0] = lred[0][0]+lred[1][0]+lred[2][0]+lred[3][0];
            p1s[b*3+1] = lred[0][1]+lred[1][1]+lred[2][1]+lred[3][1];
            p1s[b*3+2] = lred[0][2]+lred[1][2]+lred[2][2]+lred[3][2];
        }
    }
    grid.sync();

    int itex = MAXIT;
    for (int it = 0; it <= MAXIT; ++it) {
        // ---------- step A: (R,t) of body it-1, done check (uniform) ----------
        if (it == 0) {
            if (tid == 0) {
                sR[0]=1.f; sR[1]=0.f; sR[2]=0.f;
                sR[3]=0.f; sR[4]=1.f; sR[5]=0.f;
                sR[6]=0.f; sR[7]=0.f; sR[8]=1.f;
                sT[0]=0.f; sT[1]=0.f; sT[2]=0.f;
                sCtl = 0;
            }
        } else if (wave == 0) {
            const int slot  = (it-1) & 3;
            const int slot2 = (it-2) & 3;
            float a[16];
            const float* pb = &part[((slot*B + b)*64 + lane)*16];
            #pragma unroll
            for (int k = 0; k < 16; ++k) a[k] = pb[k];
            #pragma unroll
            for (int k = 0; k < 16; ++k) a[k] = wred(a[k]);
            float ec = 0.f;
            #pragma unroll
            for (int bb = 0; bb < B; ++bb)
                ec += part[((slot*B + bb)*64 + lane)*16 + 15];
            ec = wred(ec);
            float ep = 0.f;
            if (it >= 2) {
                #pragma unroll
                for (int bb = 0; bb < B; ++bb)
                    ep += part[((slot2*B + bb)*64 + lane)*16 + 15];
                ep = wred(ep);
            }
            if (lane == 0) {
                const float errcur  = ec / (float)(B*N);
                const float errprev = (it >= 2) ? ep / (float)(B*N) : 0.0f;
                const int done = (fabsf(errprev - errcur) < TOL) ? 1 : 0;
                double H[9], c1d[3], c2d[3];
                c2d[0] = (double)a[0]/N; c2d[1] = (double)a[1]/N; c2d[2] = (double)a[2]/N;
                c1d[0] = (double)a[3]/N; c1d[1] = (double)a[4]/N; c1d[2] = (double)a[5]/N;
                for (int j = 0; j < 3; ++j)
                    for (int k = 0; k < 3; ++k)
                        H[j*3+k] = (double)a[6 + j*3 + k] - (double)N * c2d[j] * c1d[k];
                compute_Rt(H, c1d, c2d, sR, sT);
                sCtl = (done || it == MAXIT) ? 1 : 0;
            }
        }
        __syncthreads();
        if (sCtl) { itex = it; break; }

        // ---------- NN: candidates = transform(buf), score-based argmin ----------
        {
            const int cb = (blk >> 1) * CC;
            const int qb = (blk & 1) * QC;
            if (tid < CC) {
                const float* cp = &buf[(b*N + cb + tid)*3];
                float cx, cy, cz;
                tf_pt(sR, sT, cp[0], cp[1], cp[2], cx, cy, cz);
                sc4[tid] = make_float4(cx, cy, cz, 0.5f*(cx*cx + cy*cy + cz*cz));
            }
            __syncthreads();
            float px[QPT], py[QPT], pz[QPT];
            float best[QPT];
            int   bi[QPT];
            #pragma unroll
            for (int k = 0; k < QPT; ++k) {
                const int q = qb + tid + BT*k;
                px[k] = p2[(b*N + q)*3 + 0];
                py[k] = p2[(b*N + q)*3 + 1];
                pz[k] = p2[(b*N + q)*3 + 2];
                best[k] = __uint_as_float(0x7f7fffffu);   // FLT_MAX
                bi[k] = 0;
            }
            #pragma unroll 4
            for (int j = 0; j < CC; ++j) {
                const float4 c = sc4[j];
                #pragma unroll
                for (int k = 0; k < QPT; ++k) {
                    float s = __builtin_fmaf(-px[k], c.x,
                              __builtin_fmaf(-py[k], c.y,
                              __builtin_fmaf(-pz[k], c.z, c.w)));
                    if (s < best[k]) { best[k] = s; bi[k] = cb + j; }
                }
            }
            #pragma unroll
            for (int k = 0; k < QPT; ++k) {
                const int q = qb + tid + BT*k;
                const float pn = px[k]*px[k] + py[k]*py[k] + pz[k]*pz[k];
                float d2 = fmaxf(__builtin_fmaf(2.0f, best[k], pn), 0.0f);
                unsigned long long K =
                    ((unsigned long long)__float_as_uint(d2) << 32) | (unsigned int)bi[k];
                // parity encoding: stale entries always lose (top bit), no resets needed
                if (it & 1) atomicMax(&nn[b*N + q], ~K);
                else        atomicMin(&nn[b*N + q],  K);
            }
        }
        grid.sync();

        // ---------- phase B: consume nn, update temp, write partial sums ----------
        {
            const int slotW = it & 3;
            float pv[16];
            #pragma unroll
            for (int k = 0; k < 16; ++k) pv[k] = 0.f;
            if (tid < RPB) {
                const int r = r0 + tid;
                const int i = r & (N-1);
                unsigned long long pk = nn[r];
                if (it & 1) pk = ~pk;
                const unsigned int dbits = (unsigned int)(pk >> 32);
                unsigned long long pk3 = nn[3*N + i];     // reference quirk: idx[-1]
                if (it & 1) pk3 = ~pk3;
                const int mi = (int)(unsigned int)(pk3 & 0xffffffffULL);
                const float* mp = &p2[(b*N + mi)*3];
                const float mx = mp[0], my = mp[1], mz = mp[2];
                const float* tp = &buf[r*3];
                float tx, ty, tz;
                tf_pt(sR, sT, tp[0], tp[1], tp[2], tx, ty, tz);
                buf[r*3+0] = tx; buf[r*3+1] = ty; buf[r*3+2] = tz;
                pv[0] = mx; pv[1] = my; pv[2] = mz;
                pv[3] = tx; pv[4] = ty; pv[5] = tz;
                pv[6] = mx*tx;  pv[7]  = mx*ty; pv[8]  = mx*tz;
                pv[9] = my*tx;  pv[10] = my*ty; pv[11] = my*tz;
                pv[12]= mz*tx;  pv[13] = mz*ty; pv[14] = mz*tz;
                pv[15]= sqrtf(__uint_as_float(dbits));
            }
            if (wave == 0) {
                #pragma unroll
                for (int k = 0; k < 16; ++k) pv[k] = wred(pv[k]);
                if (lane == 0) {
                    float* pb = &part[((slotW*B + b)*64 + blk)*16];
                    #pragma unroll
                    for (int k = 0; k < 16; ++k) pb[k] = pv[k];
                }
            }
        }
        grid.sync();
    }

    // ---------- final: _get_transform(p1, temp_final) ----------
    {
        const int fslot = itex & 3;   // proven free of concurrent readers
        float pv[12];
        #pragma unroll
        for (int k = 0; k < 12; ++k) pv[k] = 0.f;
        if (tid < RPB) {
            const int r = r0 + tid;
            const float* tp = &buf[r*3];
            float tx, ty, tz;
            tf_pt(sR, sT, tp[0], tp[1], tp[2], tx, ty, tz);  // temp after last body
            const float* pp = &p1[r*3];
            const float px = pp[0], py = pp[1], pz = pp[2];
            pv[0] = tx; pv[1] = ty; pv[2] = tz;
            pv[3] = tx*px; pv[4] = tx*py; pv[5] = tx*pz;
            pv[6] = ty*px; pv[7] = ty*py; pv[8] = ty*pz;
            pv[9] = tz*px; pv[10]= tz*py; pv[11]= tz*pz;
        }
        if (wave == 0) {
            #pragma unroll
            for (int k = 0; k < 12; ++k) pv[k] = wred(pv[k]);
            if (lane == 0) {
                float* pb = &part[((fslot*B + b)*64 + blk)*16];
                #pragma unroll
                for (int k = 0; k < 12; ++k) pb[k] = pv[k];
            }
        }
        grid.sync();
        if (blk == 0 && wave == 0) {
            float a[12];
            const float* pb = &part[((fslot*B + b)*64 + lane)*16];
            #pragma unroll
            for (int k = 0; k < 12; ++k) a[k] = pb[k];
            #pragma unroll
            for (int k = 0; k < 12; ++k) a[k] = wred(a[k]);
            if (lane == 0) {
                double H[9], c1d[3], c2d[3];
                c2d[0] = (double)a[0]/N; c2d[1] = (double)a[1]/N; c2d[2] = (double)a[2]/N;
                c1d[0] = (double)p1s[b*3+0]/N;
                c1d[1] = (double)p1s[b*3+1]/N;
                c1d[2] = (double)p1s[b*3+2]/N;
                for (int j = 0; j < 3; ++j)
                    for (int k = 0; k < 3; ++k)
                        H[j*3+k] = (double)a[3 + j*3 + k] - (double)N * c2d[j] * c1d[k];
                float Rf[9], Tf[3];
                compute_Rt(H, c1d, c2d, Rf, Tf);
                for (int i = 0; i < 3; ++i) {
                    out[b*12 + i*4 + 0] = Rf[i*3+0];
                    out[b*12 + i*4 + 1] = Rf[i*3+1];
                    out[b*12 + i*4 + 2] = Rf[i*3+2];
                    out[b*12 + i*4 + 3] = Tf[i];
                }
            }
        }
    }
}

extern "C" void kernel_launch(void* const* d_in, const int* in_sizes, int n_in,
                              void* d_out, int out_size, void* d_ws, size_t ws_size,
                              hipStream_t stream) {
    const float* p1 = (const float*)d_in[0];
    const float* p2 = (const float*)d_in[1];
    float* out = (float*)d_out;
    float* buf = (float*)d_ws;
    unsigned long long* nn = (unsigned long long*)((char*)d_ws + 98304);
    float* part = (float*)((char*)d_ws + 163840);
    float* p1s  = (float*)((char*)d_ws + 229376);

    void* args[] = { (void*)&p1, (void*)&p2, (void*)&out,
                     (void*)&buf, (void*)&nn, (void*)&part, (void*)&p1s };
    hipLaunchCooperativeKernel((const void*)icp_fused, dim3(NBLK), dim3(BT),
                               args, 0, stream);
}

// Round 3
// 341.704 us; speedup vs baseline: 2.5930x; 2.5930x over previous
//
#include <hip/hip_runtime.h>

#define B 4
#define N 2048
#define MAXIT 11        // bodies it=0..10; launch it=11 is finalize-only
#define TOL 1e-4f
#define BT 256
#define NBLK 256
#define CC 64          // candidates per nn tile
#define QPT 4          // queries per thread
#define QC (BT*QPT)    // 1024 queries per nn tile

// ---------------- workspace layout ----------------
// [0,      65536)   u64 nnA[B][N]          (slot 0, parity-encoded, never reset)
// [65536, 131072)   u64 nnB[B][N]          (slot 1, parity-encoded, never reset)
// [131072,135680)   double rc[B][12][12]   (cumulative R(9)+t(3) per batch per launch)
// [135680,135728)   float errs[12]
// [135728,135732)   int doneflag

// ---------------- 3x3 helpers (double, thread-serial) ----------------
__device__ double det3(const double* M) {
    return M[0]*(M[4]*M[8]-M[5]*M[7])
         - M[1]*(M[3]*M[8]-M[5]*M[6])
         + M[2]*(M[3]*M[7]-M[4]*M[6]);
}

__device__ void svd3x3(const double* A, double* U, double* V, double* sig) {
    double S[9];
    for (int i = 0; i < 3; ++i)
        for (int j = 0; j < 3; ++j) {
            double s = 0.0;
            for (int k = 0; k < 3; ++k) s += A[k*3+i] * A[k*3+j];
            S[i*3+j] = s;
        }
    double Vm[9] = {1,0,0, 0,1,0, 0,0,1};
    for (int sweep = 0; sweep < 30; ++sweep) {
        double off = fabs(S[1]) + fabs(S[2]) + fabs(S[5]);
        double base = fabs(S[0]) + fabs(S[4]) + fabs(S[8]);
        if (off <= 1e-15 * base) break;
        for (int pi = 0; pi < 3; ++pi) {
            const int p = (pi == 2) ? 1 : 0;
            const int q = (pi == 0) ? 1 : 2;
            double apq = S[p*3+q];
            if (apq == 0.0) continue;
            double app = S[p*3+p], aqq = S[q*3+q];
            double tau = (aqq - app) / (2.0 * apq);
            double tt  = ((tau >= 0.0) ? 1.0 : -1.0) / (fabs(tau) + sqrt(1.0 + tau*tau));
            double c = 1.0 / sqrt(1.0 + tt*tt);
            double s = tt * c;
            for (int k = 0; k < 3; ++k) {
                double skp = S[k*3+p], skq = S[k*3+q];
                S[k*3+p] = c*skp - s*skq;
                S[k*3+q] = s*skp + c*skq;
            }
            for (int k = 0; k < 3; ++k) {
                double spk = S[p*3+k], sqk = S[q*3+k];
                S[p*3+k] = c*spk - s*sqk;
                S[q*3+k] = s*spk + c*sqk;
            }
            for (int k = 0; k < 3; ++k) {
                double vkp = Vm[k*3+p], vkq = Vm[k*3+q];
                Vm[k*3+p] = c*vkp - s*vkq;
                Vm[k*3+q] = s*vkp + c*vkq;
            }
        }
    }
    double lam[3] = {S[0], S[4], S[8]};
    int ord[3] = {0, 1, 2};
    for (int i = 0; i < 2; ++i)
        for (int j = i+1; j < 3; ++j)
            if (lam[ord[j]] > lam[ord[i]]) { int tmp = ord[i]; ord[i] = ord[j]; ord[j] = tmp; }
    for (int i = 0; i < 3; ++i) {
        int o = ord[i];
        double l = lam[o] > 0.0 ? lam[o] : 0.0;
        sig[i] = sqrt(l);
        for (int k = 0; k < 3; ++k) V[k*3+i] = Vm[k*3+o];
    }
    for (int i = 0; i < 3; ++i) {
        double u0 = 0, u1 = 0, u2 = 0;
        for (int k = 0; k < 3; ++k) {
            u0 += A[0*3+k] * V[k*3+i];
            u1 += A[1*3+k] * V[k*3+i];
            u2 += A[2*3+k] * V[k*3+i];
        }
        double nrm = sqrt(u0*u0 + u1*u1 + u2*u2);
        if (nrm > 1e-300) { u0 /= nrm; u1 /= nrm; u2 /= nrm; }
        else {
            double ax = U[0], ay = U[3], az = U[6];
            double bx = U[1], by = U[4], bz = U[7];
            u0 = ay*bz - az*by; u1 = az*bx - ax*bz; u2 = ax*by - ay*bx;
        }
        U[0*3+i] = u0; U[1*3+i] = u1; U[2*3+i] = u2;
    }
}

// R from H (f64, row-major). R = V' @ U^T with det fix.
__device__ void compute_R_f64(const double* H, double* R) {
    double U[9], V[9], sig[3];
    svd3x3(H, U, V, sig);
    double d = (det3(U) * det3(V) < 0.0) ? -1.0 : 1.0;
    V[2*3+2] *= d;
    for (int i = 0; i < 3; ++i)
        for (int j = 0; j < 3; ++j) {
            double s = 0.0;
            for (int k = 0; k < 3; ++k) s += V[i*3+k] * U[j*3+k];
            R[i*3+j] = s;
        }
}

__device__ inline float wred(float v) {
    v += __shfl_down(v, 32);
    v += __shfl_down(v, 16);
    v += __shfl_down(v, 8);
    v += __shfl_down(v, 4);
    v += __shfl_down(v, 2);
    v += __shfl_down(v, 1);
    return v;   // valid on lane 0 of each wave
}

__device__ __forceinline__ void tf3(const float* __restrict__ R, const float* __restrict__ T,
                                    float x, float y, float z,
                                    float& ox, float& oy, float& oz) {
    ox = x*R[0] + y*R[3] + z*R[6] + T[0];
    oy = x*R[1] + y*R[4] + z*R[7] + T[1];
    oz = x*R[2] + y*R[5] + z*R[8] + T[2];
}

// One launch per ICP iteration. 256 blocks: b = bid>>6, blk = bid&63.
// Phase 1 (it>0): every block redundantly reduces nn[it-1] -> err, H -> SVD ->
//   incremental R,t -> composes cumulative rc[b][it] (bit-identical across blocks).
// Phase 2 (it<=10, not done): NN for iteration it, candidates = rc[it](p1) on the fly.
// Finalize (done or it==11): blk==0 blocks compute _get_transform(p1, rc[it](p1)).
__global__ void __launch_bounds__(BT) k_iter(const float* __restrict__ p1,
                                             const float* __restrict__ p2,
                                             float* __restrict__ out,
                                             unsigned long long* __restrict__ nnA,
                                             unsigned long long* __restrict__ nnB,
                                             double* __restrict__ rc,
                                             float* __restrict__ errs,
                                             int* __restrict__ doneflag,
                                             int it) {
    const int bid = blockIdx.x, tid = threadIdx.x;
    const int b = bid >> 6, blk = bid & 63;
    const int lane = tid & 63, wave = tid >> 6;

    __shared__ float4 sc4[CC];
    __shared__ float sR[9], sT[3];
    __shared__ float lred[4][16];
    __shared__ int sFin;

    if (it == 0) {
        if (tid == 0) {
            sR[0]=1.f; sR[1]=0.f; sR[2]=0.f;
            sR[3]=0.f; sR[4]=1.f; sR[5]=0.f;
            sR[6]=0.f; sR[7]=0.f; sR[8]=1.f;
            sT[0]=0.f; sT[1]=0.f; sT[2]=0.f;
            sFin = 0;
            if (bid == 0) {
                *doneflag = 0;
                for (int bb = 0; bb < B; ++bb) {   // rc[bb][0] = identity
                    double* r0 = rc + (bb*12 + 0)*12;
                    r0[0]=1; r0[1]=0; r0[2]=0; r0[3]=0; r0[4]=1; r0[5]=0;
                    r0[6]=0; r0[7]=0; r0[8]=1; r0[9]=0; r0[10]=0; r0[11]=0;
                }
            }
        }
        __syncthreads();
    } else {
        // cheap cross-launch early exit
        if (tid == 0) sFin = (*doneflag) ? 2 : 0;
        __syncthreads();
        if (sFin == 2) return;

        // ---------- phase 1: reduce nn[it-1], SVD, compose ----------
        const unsigned long long* nnR = ((it-1) & 1) ? nnB : nnA;
        const int renc = ((it-1) >> 1) & 1;
        const double* rp = rc + (b*12 + (it-1))*12;
        float cR[9], cT[3];
        #pragma unroll
        for (int k = 0; k < 9; ++k) cR[k] = (float)rp[k];
        #pragma unroll
        for (int k = 0; k < 3; ++k) cT[k] = (float)rp[9+k];

        float pv[16];
        #pragma unroll
        for (int k = 0; k < 16; ++k) pv[k] = 0.f;
        for (int i = tid; i < N; i += BT) {
            unsigned long long pk3 = nnR[3*N + i];      // reference quirk: idx[-1]
            if (renc) pk3 = ~pk3;
            const int mi = (int)(unsigned int)(pk3 & 0xffffffffULL);
            const float* mp = &p2[(b*N + mi)*3];
            const float mx = mp[0], my = mp[1], mz = mp[2];
            const float* pp = &p1[(b*N + i)*3];
            float tx, ty, tz;
            tf3(cR, cT, pp[0], pp[1], pp[2], tx, ty, tz);   // temp_{it-1}
            pv[0] += mx;  pv[1] += my;  pv[2] += mz;
            pv[3] += tx;  pv[4] += ty;  pv[5] += tz;
            pv[6] += mx*tx;  pv[7]  += mx*ty;  pv[8]  += mx*tz;
            pv[9] += my*tx;  pv[10] += my*ty;  pv[11] += my*tz;
            pv[12]+= mz*tx;  pv[13] += mz*ty;  pv[14] += mz*tz;
        }
        for (int r = tid; r < B*N; r += BT) {            // err over ALL batches
            unsigned long long pk = nnR[r];
            if (renc) pk = ~pk;
            pv[15] += sqrtf(__uint_as_float((unsigned int)(pk >> 32)));
        }
        #pragma unroll
        for (int k = 0; k < 16; ++k) pv[k] = wred(pv[k]);
        if (lane == 0) {
            #pragma unroll
            for (int k = 0; k < 16; ++k) lred[wave][k] = pv[k];
        }
        __syncthreads();
        if (tid == 0) {
            float a[16];
            #pragma unroll
            for (int k = 0; k < 16; ++k)
                a[k] = lred[0][k] + lred[1][k] + lred[2][k] + lred[3][k];
            const float errcur  = a[15] / (float)(B*N);
            const float errprev = (it >= 2) ? errs[it-2] : 0.0f;
            const int done = (fabsf(errprev - errcur) < TOL) ? 1 : 0;
            errs[it-1] = errcur;

            double c2d[3] = { (double)a[0]/N, (double)a[1]/N, (double)a[2]/N };
            double c1d[3] = { (double)a[3]/N, (double)a[4]/N, (double)a[5]/N };
            double H[9];
            for (int j = 0; j < 3; ++j)
                for (int k = 0; k < 3; ++k)
                    H[j*3+k] = (double)a[6 + j*3 + k] - (double)N * c2d[j] * c1d[k];
            double Rinc[9], tinc[3];
            compute_R_f64(H, Rinc);
            for (int j = 0; j < 3; ++j)
                tinc[j] = c2d[j] - (c1d[0]*Rinc[0*3+j] + c1d[1]*Rinc[1*3+j] + c1d[2]*Rinc[2*3+j]);
            // compose: Rc_new = Rc_old @ Rinc ; tc_new = tc_old @ Rinc + tinc
            double Rn[9], tn[3];
            for (int i = 0; i < 3; ++i)
                for (int j = 0; j < 3; ++j)
                    Rn[i*3+j] = rp[i*3+0]*Rinc[0*3+j] + rp[i*3+1]*Rinc[1*3+j] + rp[i*3+2]*Rinc[2*3+j];
            for (int j = 0; j < 3; ++j)
                tn[j] = rp[9+0]*Rinc[0*3+j] + rp[9+1]*Rinc[1*3+j] + rp[9+2]*Rinc[2*3+j] + tinc[j];
            double* rn = rc + (b*12 + it)*12;
            for (int k = 0; k < 9; ++k) { rn[k] = Rn[k]; sR[k] = (float)Rn[k]; }
            for (int k = 0; k < 3; ++k) { rn[9+k] = tn[k]; sT[k] = (float)tn[k]; }
            sFin = (done || it == MAXIT) ? 1 : 0;
        }
        __syncthreads();
    }

    if (sFin == 1) {
        // ---------- finalize: _get_transform(p1, temp_final) ----------
        if (blk != 0) return;
        float pv[16];
        #pragma unroll
        for (int k = 0; k < 16; ++k) pv[k] = 0.f;
        for (int i = tid; i < N; i += BT) {
            const float* pp = &p1[(b*N + i)*3];
            const float px = pp[0], py = pp[1], pz = pp[2];
            float tx, ty, tz;
            tf3(sR, sT, px, py, pz, tx, ty, tz);        // temp_final
            pv[0] += tx; pv[1] += ty; pv[2] += tz;
            pv[3] += px; pv[4] += py; pv[5] += pz;
            pv[6] += tx*px;  pv[7]  += tx*py;  pv[8]  += tx*pz;
            pv[9] += ty*px;  pv[10] += ty*py;  pv[11] += ty*pz;
            pv[12]+= tz*px;  pv[13] += tz*py;  pv[14] += tz*pz;
        }
        #pragma unroll
        for (int k = 0; k < 15; ++k) pv[k] = wred(pv[k]);
        if (lane == 0) {
            #pragma unroll
            for (int k = 0; k < 15; ++k) lred[wave][k] = pv[k];
        }
        __syncthreads();
        if (tid == 0) {
            float a[15];
            #pragma unroll
            for (int k = 0; k < 15; ++k)
                a[k] = lred[0][k] + lred[1][k] + lred[2][k] + lred[3][k];
            double c2d[3] = { (double)a[0]/N, (double)a[1]/N, (double)a[2]/N };
            double c1d[3] = { (double)a[3]/N, (double)a[4]/N, (double)a[5]/N };
            double H[9];
            for (int j = 0; j < 3; ++j)
                for (int k = 0; k < 3; ++k)
                    H[j*3+k] = (double)a[6 + j*3 + k] - (double)N * c2d[j] * c1d[k];
            double Rf[9];
            compute_R_f64(H, Rf);
            for (int i = 0; i < 3; ++i) {
                out[b*12 + i*4 + 0] = (float)Rf[i*3+0];
                out[b*12 + i*4 + 1] = (float)Rf[i*3+1];
                out[b*12 + i*4 + 2] = (float)Rf[i*3+2];
                const double tj = c2d[i] - (c1d[0]*Rf[0*3+i] + c1d[1]*Rf[1*3+i] + c1d[2]*Rf[2*3+i]);
                out[b*12 + i*4 + 3] = (float)tj;
            }
            *doneflag = 1;
        }
        return;
    }

    // ---------- phase 2: NN for iteration it ----------
    {
        unsigned long long* nnW = (it & 1) ? nnB : nnA;
        const int wenc = (it >> 1) & 1;
        const int cb = (blk >> 1) * CC;
        const int qb = (blk & 1) * QC;
        if (tid < CC) {
            const float* cp = &p1[(b*N + cb + tid)*3];
            float cx, cy, cz;
            tf3(sR, sT, cp[0], cp[1], cp[2], cx, cy, cz);
            sc4[tid] = make_float4(cx, cy, cz, 0.5f*(cx*cx + cy*cy + cz*cz));
        }
        __syncthreads();
        float px[QPT], py[QPT], pz[QPT];
        float best[QPT];
        int   bi[QPT];
        #pragma unroll
        for (int k = 0; k < QPT; ++k) {
            const int q = qb + tid + BT*k;
            px[k] = p2[(b*N + q)*3 + 0];
            py[k] = p2[(b*N + q)*3 + 1];
            pz[k] = p2[(b*N + q)*3 + 2];
            best[k] = __uint_as_float(0x7f7fffffu);   // FLT_MAX
            bi[k] = 0;
        }
        #pragma unroll 4
        for (int j = 0; j < CC; ++j) {
            const float4 c = sc4[j];
            #pragma unroll
            for (int k = 0; k < QPT; ++k) {
                float s = __builtin_fmaf(-px[k], c.x,
                          __builtin_fmaf(-py[k], c.y,
                          __builtin_fmaf(-pz[k], c.z, c.w)));
                if (s < best[k]) { best[k] = s; bi[k] = cb + j; }
            }
        }
        #pragma unroll
        for (int k = 0; k < QPT; ++k) {
            const int q = qb + tid + BT*k;
            const float pn = px[k]*px[k] + py[k]*py[k] + pz[k]*pz[k];
            float d2 = fmaxf(__builtin_fmaf(2.0f, best[k], pn), 0.0f);
            unsigned long long K =
                ((unsigned long long)__float_as_uint(d2) << 32) | (unsigned int)bi[k];
            if (wenc) atomicMax(&nnW[b*N + q], ~K);
            else      atomicMin(&nnW[b*N + q],  K);
        }
    }
}

extern "C" void kernel_launch(void* const* d_in, const int* in_sizes, int n_in,
                              void* d_out, int out_size, void* d_ws, size_t ws_size,
                              hipStream_t stream) {
    const float* p1 = (const float*)d_in[0];
    const float* p2 = (const float*)d_in[1];
    float* out = (float*)d_out;
    unsigned long long* nnA = (unsigned long long*)d_ws;
    unsigned long long* nnB = (unsigned long long*)((char*)d_ws + 65536);
    double* rc   = (double*)((char*)d_ws + 131072);
    float* errs  = (float*)((char*)d_ws + 135680);
    int* doneflag = (int*)((char*)d_ws + 135728);

    hipMemsetAsync(d_ws, 0xFF, 131072, stream);   // both nn slots: all-ones keys
    for (int it = 0; it <= MAXIT; ++it)
        k_iter<<<NBLK, BT, 0, stream>>>(p1, p2, out, nnA, nnB, rc, errs, doneflag, it);
}

// Round 4
// 313.206 us; speedup vs baseline: 2.8289x; 1.0910x over previous
//
#include <hip/hip_runtime.h>

#define B 4
#define N 2048
#define MAXIT 11        // bodies it=0..10; launch it=11 is finalize-only
#define TOL 1e-4f
#define BT 256
#define NBLK 256
#define CC 64          // candidates per nn tile
#define QPT 4          // queries per thread
#define QC (BT*QPT)    // 1024 queries per nn tile
#define RPT 8          // rows per thread in phase-1 (N/BT)

// ---------------- workspace layout ----------------
// [0,      65536)   u64 nnA[B][N]          (slot 0, parity-encoded, never reset)
// [65536, 131072)   u64 nnB[B][N]          (slot 1, parity-encoded, never reset)
// [131072,135680)   double rc[B][12][12]   (cumulative R(9)+t(3) per batch per launch)
// [135680,135728)   float errs[12]
// [135728,135732)   int doneflag

// ---------------- 3x3 helpers (double, thread-serial) ----------------
__device__ double det3(const double* M) {
    return M[0]*(M[4]*M[8]-M[5]*M[7])
         - M[1]*(M[3]*M[8]-M[5]*M[6])
         + M[2]*(M[3]*M[7]-M[4]*M[6]);
}

__device__ void svd3x3(const double* A, double* U, double* V, double* sig) {
    double S[9];
    for (int i = 0; i < 3; ++i)
        for (int j = 0; j < 3; ++j) {
            double s = 0.0;
            for (int k = 0; k < 3; ++k) s += A[k*3+i] * A[k*3+j];
            S[i*3+j] = s;
        }
    double Vm[9] = {1,0,0, 0,1,0, 0,0,1};
    for (int sweep = 0; sweep < 30; ++sweep) {
        double off = fabs(S[1]) + fabs(S[2]) + fabs(S[5]);
        double base = fabs(S[0]) + fabs(S[4]) + fabs(S[8]);
        if (off <= 1e-15 * base) break;
        for (int pi = 0; pi < 3; ++pi) {
            const int p = (pi == 2) ? 1 : 0;
            const int q = (pi == 0) ? 1 : 2;
            double apq = S[p*3+q];
            if (apq == 0.0) continue;
            double app = S[p*3+p], aqq = S[q*3+q];
            double tau = (aqq - app) / (2.0 * apq);
            double tt  = ((tau >= 0.0) ? 1.0 : -1.0) / (fabs(tau) + sqrt(1.0 + tau*tau));
            double c = 1.0 / sqrt(1.0 + tt*tt);
            double s = tt * c;
            for (int k = 0; k < 3; ++k) {
                double skp = S[k*3+p], skq = S[k*3+q];
                S[k*3+p] = c*skp - s*skq;
                S[k*3+q] = s*skp + c*skq;
            }
            for (int k = 0; k < 3; ++k) {
                double spk = S[p*3+k], sqk = S[q*3+k];
                S[p*3+k] = c*spk - s*sqk;
                S[q*3+k] = s*spk + c*sqk;
            }
            for (int k = 0; k < 3; ++k) {
                double vkp = Vm[k*3+p], vkq = Vm[k*3+q];
                Vm[k*3+p] = c*vkp - s*vkq;
                Vm[k*3+q] = s*vkp + c*vkq;
            }
        }
    }
    double lam[3] = {S[0], S[4], S[8]};
    int ord[3] = {0, 1, 2};
    for (int i = 0; i < 2; ++i)
        for (int j = i+1; j < 3; ++j)
            if (lam[ord[j]] > lam[ord[i]]) { int tmp = ord[i]; ord[i] = ord[j]; ord[j] = tmp; }
    for (int i = 0; i < 3; ++i) {
        int o = ord[i];
        double l = lam[o] > 0.0 ? lam[o] : 0.0;
        sig[i] = sqrt(l);
        for (int k = 0; k < 3; ++k) V[k*3+i] = Vm[k*3+o];
    }
    for (int i = 0; i < 3; ++i) {
        double u0 = 0, u1 = 0, u2 = 0;
        for (int k = 0; k < 3; ++k) {
            u0 += A[0*3+k] * V[k*3+i];
            u1 += A[1*3+k] * V[k*3+i];
            u2 += A[2*3+k] * V[k*3+i];
        }
        double nrm = sqrt(u0*u0 + u1*u1 + u2*u2);
        if (nrm > 1e-300) { u0 /= nrm; u1 /= nrm; u2 /= nrm; }
        else {
            double ax = U[0], ay = U[3], az = U[6];
            double bx = U[1], by = U[4], bz = U[7];
            u0 = ay*bz - az*by; u1 = az*bx - ax*bz; u2 = ax*by - ay*bx;
        }
        U[0*3+i] = u0; U[1*3+i] = u1; U[2*3+i] = u2;
    }
}

// R = V @ U^T (reference's R with the V[2][2]*=d quirk). Fast path: when
// det(H) > 0 the quirk is a no-op (d=+1) and R is exactly the transpose of
// the orthogonal polar factor of H -> Newton polar iteration, fixed 10
// iterations (uniform control flow, bit-identical across blocks), ~1.3us
// vs ~10us for Jacobi SVD. Fallback (det<=eps): exact Jacobi path.
__device__ void compute_R_f64(const double* H, double* R) {
    double nf = 0.0;
    for (int k = 0; k < 9; ++k) nf += H[k]*H[k];
    if (nf > 0.0) {
        const double sc = 1.0 / sqrt(nf * (1.0/3.0));
        double X[9];
        #pragma unroll
        for (int k = 0; k < 9; ++k) X[k] = H[k] * sc;
        const double d0 = det3(X);
        if (d0 > 1e-12) {
            for (int iter = 0; iter < 10; ++iter) {
                const double dt = det3(X);
                const double g = (iter < 4) ? cbrt(1.0 / dt) : 1.0;
                double Y[9];
                #pragma unroll
                for (int k = 0; k < 9; ++k) Y[k] = g * X[k];
                double C[9];                       // cofactor matrix: Y^{-T} = C/det(Y)
                C[0] = Y[4]*Y[8]-Y[5]*Y[7]; C[1] = Y[5]*Y[6]-Y[3]*Y[8]; C[2] = Y[3]*Y[7]-Y[4]*Y[6];
                C[3] = Y[2]*Y[7]-Y[1]*Y[8]; C[4] = Y[0]*Y[8]-Y[2]*Y[6]; C[5] = Y[1]*Y[6]-Y[0]*Y[7];
                C[6] = Y[1]*Y[5]-Y[2]*Y[4]; C[7] = Y[2]*Y[3]-Y[0]*Y[5]; C[8] = Y[0]*Y[4]-Y[1]*Y[3];
                const double inv = 1.0 / (dt * g * g * g);
                #pragma unroll
                for (int k = 0; k < 9; ++k) X[k] = 0.5 * (Y[k] + C[k] * inv);
            }
            // X -> U V^T ; reference R = V U^T = X^T
            R[0]=X[0]; R[1]=X[3]; R[2]=X[6];
            R[3]=X[1]; R[4]=X[4]; R[5]=X[7];
            R[6]=X[2]; R[7]=X[5]; R[8]=X[8];
            return;
        }
    }
    // fallback: full Jacobi SVD, matches reference incl. element quirk
    double U[9], V[9], sig[3];
    svd3x3(H, U, V, sig);
    double d = (det3(U) * det3(V) < 0.0) ? -1.0 : 1.0;
    V[2*3+2] *= d;
    for (int i = 0; i < 3; ++i)
        for (int j = 0; j < 3; ++j) {
            double s = 0.0;
            for (int k = 0; k < 3; ++k) s += V[i*3+k] * U[j*3+k];
            R[i*3+j] = s;
        }
}

__device__ inline float wred(float v) {
    v += __shfl_down(v, 32);
    v += __shfl_down(v, 16);
    v += __shfl_down(v, 8);
    v += __shfl_down(v, 4);
    v += __shfl_down(v, 2);
    v += __shfl_down(v, 1);
    return v;   // valid on lane 0 of each wave
}

__device__ __forceinline__ void tf3(const float* __restrict__ R, const float* __restrict__ T,
                                    float x, float y, float z,
                                    float& ox, float& oy, float& oz) {
    ox = x*R[0] + y*R[3] + z*R[6] + T[0];
    oy = x*R[1] + y*R[4] + z*R[7] + T[1];
    oz = x*R[2] + y*R[5] + z*R[8] + T[2];
}

// One launch per ICP iteration. 256 blocks: b = bid>>6, blk = bid&63.
// Phase 1 (it>0): every block redundantly reduces nn[it-1] -> err, H -> polar ->
//   incremental R,t -> composes cumulative rc[b][it] (bit-identical across blocks).
// Phase 2 (it<=10, not done): NN for iteration it, candidates = rc[it](p1) on the fly.
// Finalize (done or it==11): blk==0 blocks compute _get_transform(p1, rc[it](p1)).
__global__ void __launch_bounds__(BT) k_iter(const float* __restrict__ p1,
                                             const float* __restrict__ p2,
                                             float* __restrict__ out,
                                             unsigned long long* __restrict__ nnA,
                                             unsigned long long* __restrict__ nnB,
                                             double* __restrict__ rc,
                                             float* __restrict__ errs,
                                             int* __restrict__ doneflag,
                                             int it) {
    const int bid = blockIdx.x, tid = threadIdx.x;
    const int b = bid >> 6, blk = bid & 63;
    const int lane = tid & 63, wave = tid >> 6;

    __shared__ float4 sc4[CC];
    __shared__ float sR[9], sT[3];
    __shared__ float lred[4][16];
    __shared__ int sFin;

    if (it == 0) {
        if (tid == 0) {
            sR[0]=1.f; sR[1]=0.f; sR[2]=0.f;
            sR[3]=0.f; sR[4]=1.f; sR[5]=0.f;
            sR[6]=0.f; sR[7]=0.f; sR[8]=1.f;
            sT[0]=0.f; sT[1]=0.f; sT[2]=0.f;
            sFin = 0;
            if (bid == 0) {
                *doneflag = 0;
                for (int bb = 0; bb < B; ++bb) {   // rc[bb][0] = identity
                    double* r0 = rc + (bb*12 + 0)*12;
                    r0[0]=1; r0[1]=0; r0[2]=0; r0[3]=0; r0[4]=1; r0[5]=0;
                    r0[6]=0; r0[7]=0; r0[8]=1; r0[9]=0; r0[10]=0; r0[11]=0;
                }
            }
        }
        __syncthreads();
    } else {
        // cheap cross-launch early exit
        if (tid == 0) sFin = (*doneflag) ? 2 : 0;
        __syncthreads();
        if (sFin == 2) return;

        // ---------- phase 1: reduce nn[it-1], polar, compose ----------
        const unsigned long long* nnR = ((it-1) & 1) ? nnB : nnA;
        const int renc = ((it-1) >> 1) & 1;
        const double* rp = rc + (b*12 + (it-1))*12;
        float cR[9], cT[3];
        #pragma unroll
        for (int k = 0; k < 9; ++k) cR[k] = (float)rp[k];
        #pragma unroll
        for (int k = 0; k < 3; ++k) cT[k] = (float)rp[9+k];

        float pv[16];
        #pragma unroll
        for (int k = 0; k < 16; ++k) pv[k] = 0.f;

        // batched loads: 8 independent nn reads, then 8 gathered p2 reads,
        // then 8 p1 reads -> two latency waves instead of 8 serial chains
        unsigned long long pk3[RPT];
        #pragma unroll
        for (int u = 0; u < RPT; ++u)
            pk3[u] = nnR[3*N + (tid + u*BT)];      // reference quirk: idx[-1]
        int mi[RPT];
        #pragma unroll
        for (int u = 0; u < RPT; ++u) {
            const unsigned long long k3 = renc ? ~pk3[u] : pk3[u];
            mi[u] = (int)(unsigned int)(k3 & 0xffffffffULL);
        }
        float mxa[RPT], mya[RPT], mza[RPT];
        #pragma unroll
        for (int u = 0; u < RPT; ++u) {
            const float* mp = &p2[(b*N + mi[u])*3];
            mxa[u] = mp[0]; mya[u] = mp[1]; mza[u] = mp[2];
        }
        float pxa[RPT], pya[RPT], pza[RPT];
        #pragma unroll
        for (int u = 0; u < RPT; ++u) {
            const float* pp = &p1[(b*N + (tid + u*BT))*3];
            pxa[u] = pp[0]; pya[u] = pp[1]; pza[u] = pp[2];
        }
        #pragma unroll
        for (int u = 0; u < RPT; ++u) {
            float tx, ty, tz;
            tf3(cR, cT, pxa[u], pya[u], pza[u], tx, ty, tz);   // temp_{it-1}
            const float mx = mxa[u], my = mya[u], mz = mza[u];
            pv[0] += mx;  pv[1] += my;  pv[2] += mz;
            pv[3] += tx;  pv[4] += ty;  pv[5] += tz;
            pv[6] += mx*tx;  pv[7]  += mx*ty;  pv[8]  += mx*tz;
            pv[9] += my*tx;  pv[10] += my*ty;  pv[11] += my*tz;
            pv[12]+= mz*tx;  pv[13] += mz*ty;  pv[14] += mz*tz;
        }
        for (int r = tid; r < B*N; r += BT) {            // err over ALL batches
            unsigned long long pk = nnR[r];
            if (renc) pk = ~pk;
            pv[15] += sqrtf(__uint_as_float((unsigned int)(pk >> 32)));
        }
        #pragma unroll
        for (int k = 0; k < 16; ++k) pv[k] = wred(pv[k]);
        if (lane == 0) {
            #pragma unroll
            for (int k = 0; k < 16; ++k) lred[wave][k] = pv[k];
        }
        __syncthreads();
        if (tid == 0) {
            float a[16];
            #pragma unroll
            for (int k = 0; k < 16; ++k)
                a[k] = lred[0][k] + lred[1][k] + lred[2][k] + lred[3][k];
            const float errcur  = a[15] / (float)(B*N);
            const float errprev = (it >= 2) ? errs[it-2] : 0.0f;
            const int done = (fabsf(errprev - errcur) < TOL) ? 1 : 0;
            errs[it-1] = errcur;

            double c2d[3] = { (double)a[0]/N, (double)a[1]/N, (double)a[2]/N };
            double c1d[3] = { (double)a[3]/N, (double)a[4]/N, (double)a[5]/N };
            double H[9];
            for (int j = 0; j < 3; ++j)
                for (int k = 0; k < 3; ++k)
                    H[j*3+k] = (double)a[6 + j*3 + k] - (double)N * c2d[j] * c1d[k];
            double Rinc[9], tinc[3];
            compute_R_f64(H, Rinc);
            for (int j = 0; j < 3; ++j)
                tinc[j] = c2d[j] - (c1d[0]*Rinc[0*3+j] + c1d[1]*Rinc[1*3+j] + c1d[2]*Rinc[2*3+j]);
            // compose: Rc_new = Rc_old @ Rinc ; tc_new = tc_old @ Rinc + tinc
            double Rn[9], tn[3];
            for (int i = 0; i < 3; ++i)
                for (int j = 0; j < 3; ++j)
                    Rn[i*3+j] = rp[i*3+0]*Rinc[0*3+j] + rp[i*3+1]*Rinc[1*3+j] + rp[i*3+2]*Rinc[2*3+j];
            for (int j = 0; j < 3; ++j)
                tn[j] = rp[9+0]*Rinc[0*3+j] + rp[9+1]*Rinc[1*3+j] + rp[9+2]*Rinc[2*3+j] + tinc[j];
            double* rn = rc + (b*12 + it)*12;
            for (int k = 0; k < 9; ++k) { rn[k] = Rn[k]; sR[k] = (float)Rn[k]; }
            for (int k = 0; k < 3; ++k) { rn[9+k] = tn[k]; sT[k] = (float)tn[k]; }
            sFin = (done || it == MAXIT) ? 1 : 0;
        }
        __syncthreads();
    }

    if (sFin == 1) {
        // ---------- finalize: _get_transform(p1, temp_final) ----------
        if (blk != 0) return;
        float pv[16];
        #pragma unroll
        for (int k = 0; k < 16; ++k) pv[k] = 0.f;
        for (int i = tid; i < N; i += BT) {
            const float* pp = &p1[(b*N + i)*3];
            const float px = pp[0], py = pp[1], pz = pp[2];
            float tx, ty, tz;
            tf3(sR, sT, px, py, pz, tx, ty, tz);        // temp_final
            pv[0] += tx; pv[1] += ty; pv[2] += tz;
            pv[3] += px; pv[4] += py; pv[5] += pz;
            pv[6] += tx*px;  pv[7]  += tx*py;  pv[8]  += tx*pz;
            pv[9] += ty*px;  pv[10] += ty*py;  pv[11] += ty*pz;
            pv[12]+= tz*px;  pv[13] += tz*py;  pv[14] += tz*pz;
        }
        #pragma unroll
        for (int k = 0; k < 15; ++k) pv[k] = wred(pv[k]);
        if (lane == 0) {
            #pragma unroll
            for (int k = 0; k < 15; ++k) lred[wave][k] = pv[k];
        }
        __syncthreads();
        if (tid == 0) {
            float a[15];
            #pragma unroll
            for (int k = 0; k < 15; ++k)
                a[k] = lred[0][k] + lred[1][k] + lred[2][k] + lred[3][k];
            double c2d[3] = { (double)a[0]/N, (double)a[1]/N, (double)a[2]/N };
            double c1d[3] = { (double)a[3]/N, (double)a[4]/N, (double)a[5]/N };
            double H[9];
            for (int j = 0; j < 3; ++j)
                for (int k = 0; k < 3; ++k)
                    H[j*3+k] = (double)a[6 + j*3 + k] - (double)N * c2d[j] * c1d[k];
            double Rf[9];
            compute_R_f64(H, Rf);
            for (int i = 0; i < 3; ++i) {
                out[b*12 + i*4 + 0] = (float)Rf[i*3+0];
                out[b*12 + i*4 + 1] = (float)Rf[i*3+1];
                out[b*12 + i*4 + 2] = (float)Rf[i*3+2];
                const double tj = c2d[i] - (c1d[0]*Rf[0*3+i] + c1d[1]*Rf[1*3+i] + c1d[2]*Rf[2*3+i]);
                out[b*12 + i*4 + 3] = (float)tj;
            }
            *doneflag = 1;
        }
        return;
    }

    // ---------- phase 2: NN for iteration it ----------
    {
        unsigned long long* nnW = (it & 1) ? nnB : nnA;
        const int wenc = (it >> 1) & 1;
        const int cb = (blk >> 1) * CC;
        const int qb = (blk & 1) * QC;
        if (tid < CC) {
            const float* cp = &p1[(b*N + cb + tid)*3];
            float cx, cy, cz;
            tf3(sR, sT, cp[0], cp[1], cp[2], cx, cy, cz);
            sc4[tid] = make_float4(cx, cy, cz, 0.5f*(cx*cx + cy*cy + cz*cz));
        }
        __syncthreads();
        float px[QPT], py[QPT], pz[QPT];
        float best[QPT];
        int   bi[QPT];
        #pragma unroll
        for (int k = 0; k < QPT; ++k) {
            const int q = qb + tid + BT*k;
            px[k] = p2[(b*N + q)*3 + 0];
            py[k] = p2[(b*N + q)*3 + 1];
            pz[k] = p2[(b*N + q)*3 + 2];
            best[k] = __uint_as_float(0x7f7fffffu);   // FLT_MAX
            bi[k] = 0;
        }
        #pragma unroll 4
        for (int j = 0; j < CC; ++j) {
            const float4 c = sc4[j];
            #pragma unroll
            for (int k = 0; k < QPT; ++k) {
                float s = __builtin_fmaf(-px[k], c.x,
                          __builtin_fmaf(-py[k], c.y,
                          __builtin_fmaf(-pz[k], c.z, c.w)));
                if (s < best[k]) { best[k] = s; bi[k] = cb + j; }
            }
        }
        #pragma unroll
        for (int k = 0; k < QPT; ++k) {
            const int q = qb + tid + BT*k;
            const float pn = px[k]*px[k] + py[k]*py[k] + pz[k]*pz[k];
            float d2 = fmaxf(__builtin_fmaf(2.0f, best[k], pn), 0.0f);
            unsigned long long K =
                ((unsigned long long)__float_as_uint(d2) << 32) | (unsigned int)bi[k];
            if (wenc) atomicMax(&nnW[b*N + q], ~K);
            else      atomicMin(&nnW[b*N + q],  K);
        }
    }
}

extern "C" void kernel_launch(void* const* d_in, const int* in_sizes, int n_in,
                              void* d_out, int out_size, void* d_ws, size_t ws_size,
                              hipStream_t stream) {
    const float* p1 = (const float*)d_in[0];
    const float* p2 = (const float*)d_in[1];
    float* out = (float*)d_out;
    unsigned long long* nnA = (unsigned long long*)d_ws;
    unsigned long long* nnB = (unsigned long long*)((char*)d_ws + 65536);
    double* rc   = (double*)((char*)d_ws + 131072);
    float* errs  = (float*)((char*)d_ws + 135680);
    int* doneflag = (int*)((char*)d_ws + 135728);

    hipMemsetAsync(d_ws, 0xFF, 131072, stream);   // both nn slots: all-ones keys
    for (int it = 0; it <= MAXIT; ++it)
        k_iter<<<NBLK, BT, 0, stream>>>(p1, p2, out, nnA, nnB, rc, errs, doneflag, it);
}